// Round 11
// baseline (298.493 us; speedup 1.0000x reference)
//
#include <hip/hip_runtime.h>

#define B_ 4
#define N_ 4096
#define D_ 1536
#define H_ 512
#define K_ 8
#define M_ (B_*N_)          // 16384
#define R2_ 160000.0f       // 400^2
#define CAP 192             // max neighbors tracked per node (mean deg ~32, P(>192)~0)

typedef __attribute__((ext_vector_type(8))) short bf16x8;
typedef __attribute__((ext_vector_type(4))) float f32x4;
typedef __attribute__((ext_vector_type(2))) float f32x2;

__device__ __forceinline__ unsigned short f2bf(float f) {
  union { float f; unsigned u; } v; v.f = f;
  unsigned r = (v.u + 0x7FFFu + ((v.u >> 16) & 1u)) >> 16;
  return (unsigned short)r;
}

typedef const __attribute__((address_space(1))) unsigned int gas_u32;
typedef __attribute__((address_space(3))) unsigned int las_u32;
__device__ __forceinline__ void gl_lds16(const unsigned short* g, unsigned short* l) {
  __builtin_amdgcn_global_load_lds((gas_u32*)g, (las_u32*)l, 16, 0, 0);
}

// ---------------- K0: prepcast — cast+rownorm stream, weight transposes, anchor prep ------
#define CAST_BLKS 4096

__global__ __launch_bounds__(256) void k_prepcast(
    const float* __restrict__ images, const float* __restrict__ anchors,
    const float* __restrict__ Wf, const float* __restrict__ Wg, const float* __restrict__ Ws,
    unsigned short* __restrict__ imgs_bf, float* __restrict__ inv_norm,
    unsigned short* __restrict__ WfT, unsigned short* __restrict__ WgsT,
    unsigned short* __restrict__ ancT, float* __restrict__ invanorm) {
  int tid = threadIdx.x;
  if (blockIdx.x >= CAST_BLKS) {
    int bi = blockIdx.x - CAST_BLKS;
    if (bi < 320) {
      // ---- weight transpose ----
      __shared__ float t[64][65];
      int bx = bi & 7, by = bi >> 3;
      const float* W; unsigned short* WT; int kt, outStride, outOff;
      if (by < 24)      { W = Wf; WT = WfT;  kt = by;      outStride = D_;   outOff = 0; }
      else if (by < 32) { W = Wg; WT = WgsT; kt = by - 24; outStride = 1024; outOff = 0; }
      else              { W = Ws; WT = WgsT; kt = by - 32; outStride = 1024; outOff = 512; }
      int tx = tid & 63, ty = tid >> 6;
      #pragma unroll
      for (int r = 0; r < 64; r += 4)
        t[ty + r][tx] = W[(size_t)(kt*64 + ty + r)*H_ + bx*64 + tx];
      __syncthreads();
      #pragma unroll
      for (int r = 0; r < 64; r += 4) {
        int n = bx*64 + ty + r;
        WT[(size_t)n*outStride + outOff + kt*64 + tx] = f2bf(t[tx][ty + r]);
      }
      return;
    }
    // ---- anchor prep: bf16 row k of ancT (+ zero row k+8), 1/norm ----
    __shared__ float red[4];
    int k = bi - 320;
    float s = 0.f;
    for (int i = tid; i < D_; i += 256) {
      float v = anchors[k*D_ + i];
      s += v*v;
      ancT[(size_t)k*D_ + i] = f2bf(v);
      ancT[(size_t)(k+8)*D_ + i] = 0;     // zero anchors for MFMA cols 8..15
    }
    #pragma unroll
    for (int off = 32; off; off >>= 1) s += __shfl_down(s, off);
    if ((tid & 63) == 0) red[tid >> 6] = s;
    __syncthreads();
    if (tid == 0) invanorm[k] = 1.0f / fmaxf(sqrtf(red[0]+red[1]+red[2]+red[3]), 1e-12f);
    return;
  }
  // ---- cast + row norm: one row per wave (16384 waves -> full TLP, ~BW-bound) ----
  int lane = tid & 63, w = tid >> 6;
  int row = blockIdx.x*4 + w;
  const float4* xr = (const float4*)(images + (size_t)row*D_);
  ushort4* ob = (ushort4*)(imgs_bf + (size_t)row*D_);
  float nrm = 0.f;
  #pragma unroll
  for (int it = 0; it < 6; it++) {
    float4 x = xr[lane + 64*it];
    nrm += x.x*x.x + x.y*x.y + x.z*x.z + x.w*x.w;
    ushort4 s;
    s.x = f2bf(x.x); s.y = f2bf(x.y); s.z = f2bf(x.z); s.w = f2bf(x.w);
    ob[lane + 64*it] = s;
  }
  #pragma unroll
  for (int off = 32; off; off >>= 1) nrm += __shfl_down(nrm, off);
  if (lane == 0) inv_norm[row] = 1.0f / fmaxf(sqrtf(nrm), 1e-12f);
}

// ---------------- GEMM: C(16384 x 512) = A(16384 x Kdim) @ BT^T ----------------
// XCD-pinned remap (R8) + 3-buffer counted-vmcnt pipeline (R9/R10) + NEW: DMA-mirror
// FRAGMENT-MAJOR LDS layout. R10 lesson: pipeline depth was neutral -> step time is
// LDS-read-bound: old row-major [row][k] layout had rows at 64B stride, so every
// ds_read_b128 fragment read (lanes 0-15 at row*64 + quad*16) was ~8-way bank-conflicted
// (SQ_LDS_BANK_CONFLICT 3.4M/dispatch; 64 reads x 12cyc x 2.9 = 2.2k cyc/step-pair =
// the observed stall). Fix: stage with lane mapping (rowc=lane&15, seg=lane>>4) so LDS
// chunk c holds [quad][l15] fragment order -> every read is wave-uniform base + lane*16
// (2 lanes/bank = free). Global coalescing preserved: lanes {l,l+16,l+32,l+48} cover one
// row's 64B contiguously within the same instruction. Fragment contents per lane identical.
#define BM 128
#define BN 128
#define BK 32

__global__ __launch_bounds__(256) void k_gemm(
    const unsigned short* __restrict__ A, const unsigned short* __restrict__ BT,
    int Kdim, int mode, const float* __restrict__ bias, const float* __restrict__ Wpos,
    const float* __restrict__ positions, unsigned short* __restrict__ AB,
    unsigned char* __restrict__ P, const unsigned short* __restrict__ ancT,
    const float* __restrict__ invnorm, const float* __restrict__ invanorm,
    float* __restrict__ out) {
  __shared__ __align__(16) unsigned short As[3][BM*BK];   // 3 x 8 KB
  __shared__ __align__(16) unsigned short Bs[3][BN*BK];
  __shared__ float colsum[BN];
  int tid = threadIdx.x;
  int lane = tid & 63, wv = tid >> 6;
  int l15 = lane & 15, quad = lane >> 4;
  int bx = blockIdx.x;

  int wm = wv >> 1, wn = wv & 1;
  // XCD-pinned: xcd = bx&7; j = bx>>3 walks 64 blocks on this XCD as 16 A-tiles x 4 bn.
  int j = bx >> 3;
  int bm = (bx & 7) + 8*(j >> 2), bn = j & 3;
  int m0 = bm*BM, n0 = bn*BN;

  const bool doC = (mode == 0) && (bn == 0);   // block-uniform

  f32x4 acc[4][4] = {};
  f32x4 cacc[2] = {};                          // concept accumulators (bn==0 blocks)
  const unsigned short* anc = ancT + l15*D_ + quad*8;  // anchor row l15 (rows 8..15 zero)

  int c = wv*2;
  // fragment-major staging: lane supplies row (lane&15), k-slice (lane>>4)*8 of its chunk
  int rowc = lane & 15, seg = lane >> 4;
  const unsigned short* gA0 = A  + (size_t)(m0 + c*16 + rowc)*Kdim + seg*8;
  const unsigned short* gA1 = gA0 + (size_t)16*Kdim;
  const unsigned short* gB0 = BT + (size_t)(n0 + c*16 + rowc)*Kdim + seg*8;
  const unsigned short* gB1 = gB0 + (size_t)16*Kdim;

#define STAGE(b) do { \
    unsigned short* nA = As[b] + c*512; \
    unsigned short* nB = Bs[b] + c*512; \
    gl_lds16(gA0, nA); gl_lds16(gA1, nA + 512); \
    gl_lds16(gB0, nB); gl_lds16(gB1, nB + 512); \
    gA0 += BK; gA1 += BK; gB0 += BK; gB1 += BK; } while (0)

  int nk = Kdim / BK;
  union { uint4 u; bf16x8 h; } ancCur, ancNext;
  // prologue: anchor frag 0 (asm, issued FIRST so it retires before stage(0)) + tiles 0,1
  if (doC)
    asm volatile("global_load_dwordx4 %0, %1, off" : "=v"(ancNext.u) : "v"(anc) : "memory");
  STAGE(0);
  STAGE(1);
  const unsigned short* ancp = anc + BK;

  int cb = 0, nb = 2;
  for (int kt = 0; kt < nk; kt++) {
    if (kt + 1 < nk) asm volatile("s_waitcnt vmcnt(4)" ::: "memory");
    else             asm volatile("s_waitcnt vmcnt(0)" ::: "memory");
    __builtin_amdgcn_s_barrier();
    asm volatile("" ::: "memory");   // pin following LDS reads below the barrier

    ancCur = ancNext;
    if (doC && kt + 1 < nk) {
      asm volatile("global_load_dwordx4 %0, %1, off" : "=v"(ancNext.u) : "v"(ancp) : "memory");
      ancp += BK;
    }
    if (kt + 2 < nk) { STAGE(nb); nb = (nb + 1 == 3) ? 0 : nb + 1; }

    const unsigned short* Ab = As[cb];
    const unsigned short* Bb = Bs[cb];
    cb = (cb + 1 == 3) ? 0 : cb + 1;

    bf16x8 aF[4], bF[4];
    #pragma unroll
    for (int f = 0; f < 4; f++)
      aF[f] = *(const bf16x8*)&Ab[(wm*4 + f)*512 + lane*8];   // linear: base + lane*16B
    #pragma unroll
    for (int f = 0; f < 4; f++)
      bF[f] = *(const bf16x8*)&Bb[(wn*4 + f)*512 + lane*8];
    #pragma unroll
    for (int mi = 0; mi < 4; mi++)
      #pragma unroll
      for (int ni = 0; ni < 4; ni++)
        acc[mi][ni] = __builtin_amdgcn_mfma_f32_16x16x32_bf16(aF[mi], bF[ni], acc[mi][ni], 0, 0, 0);

    if (doC) {
      bf16x8 ancF = ancCur.h;
      if (wn == 0) {   // wave-uniform: rows wm*64 + 0..31
        cacc[0] = __builtin_amdgcn_mfma_f32_16x16x32_bf16(aF[0], ancF, cacc[0], 0, 0, 0);
        cacc[1] = __builtin_amdgcn_mfma_f32_16x16x32_bf16(aF[1], ancF, cacc[1], 0, 0, 0);
      } else {         // rows wm*64 + 32..63
        cacc[0] = __builtin_amdgcn_mfma_f32_16x16x32_bf16(aF[2], ancF, cacc[0], 0, 0, 0);
        cacc[1] = __builtin_amdgcn_mfma_f32_16x16x32_bf16(aF[3], ancF, cacc[1], 0, 0, 0);
      }
    }
  }
#undef STAGE

  if (doC) {
    // cacc C layout: col k = l15, row = quad*4 + reg within group f.
    float invA = (l15 < K_) ? invanorm[l15] : 0.f;
    float part = 0.f;
    #pragma unroll
    for (int f = 0; f < 2; f++) {
      const float4 q = *(const float4*)&invnorm[m0 + wm*64 + wn*32 + f*16 + quad*4];
      part += cacc[f][0]*q.x + cacc[f][1]*q.y + cacc[f][2]*q.z + cacc[f][3]*q.w;
    }
    part *= invA;
    part += __shfl_down(part, 32);
    part += __shfl_down(part, 16);
    if (lane < K_) atomicAdd(out + (m0 >> 12)*(H_+K_) + H_ + lane, part * (1.0f/N_));
  }

  if (mode == 0) {
    float bz[4], w0v[4], w1v[4];
    #pragma unroll
    for (int ni = 0; ni < 4; ni++) {
      int gh = n0 + wn*64 + ni*16 + l15;
      bz[ni] = bias[gh]; w0v[ni] = Wpos[gh]; w1v[ni] = Wpos[H_ + gh];
    }
    // As[0] (tile consumed 2+ barriers ago) reused as wave-private bounce scratch
    float* sb = ((float*)As[0]) + wv*256;       // 1 KB wave-private scratch
    int col4 = n0 + wn*64 + l15*4;              // base of this lane's 4 consecutive cols
    #pragma unroll
    for (int mi = 0; mi < 4; mi++) {
      #pragma unroll
      for (int r = 0; r < 4; r++) {
        int gm = m0 + wm*64 + mi*16 + quad*4 + r;
        float2 p = ((const float2*)positions)[gm];
        #pragma unroll
        for (int ni = 0; ni < 4; ni++) {
          float v = acc[mi][ni][r] + bz[ni] + p.x*w0v[ni] + p.y*w1v[ni];
          sb[quad*64 + ni*16 + l15] = v;        // ds_write_b32 x4 (wave-local)
        }
        f32x4 q = *(f32x4*)&sb[quad*64 + l15*4];  // ds_read_b128: 4 consecutive cols
        uint2 o;
        o.x = ((unsigned)f2bf(q[1]) << 16) | f2bf(q[0]);
        o.y = ((unsigned)f2bf(q[3]) << 16) | f2bf(q[2]);
        *(uint2*)&AB[(size_t)gm*1024 + 512 + col4] = o;   // feat bf16 (pre-relu, gemm2 A-half)
        float e0 = fminf(fmaxf(q[0], 0.f)*0.015625f, 448.f);
        float e1 = fminf(fmaxf(q[1], 0.f)*0.015625f, 448.f);
        float e2 = fminf(fmaxf(q[2], 0.f)*0.015625f, 448.f);
        float e3 = fminf(fmaxf(q[3], 0.f)*0.015625f, 448.f);
        int u = __builtin_amdgcn_cvt_pk_fp8_f32(e0, e1, 0, false);
        u     = __builtin_amdgcn_cvt_pk_fp8_f32(e2, e3, u, true);
        *(unsigned*)(P + (size_t)gm*512 + col4) = (unsigned)u;  // relu(feat)/64 fp8
      }
    }
  } else {
    if (tid < BN) colsum[tid] = 0.f;
    __syncthreads();
    #pragma unroll
    for (int ni = 0; ni < 4; ni++) {
      float s = 0.f;
      #pragma unroll
      for (int mi = 0; mi < 4; mi++) {
        #pragma unroll
        for (int r = 0; r < 4; r++) s += fmaxf(acc[mi][ni][r], 0.f);
      }
      s += __shfl_down(s, 32);
      s += __shfl_down(s, 16);
      if (quad == 0) atomicAdd(&colsum[wn*64 + ni*16 + l15], s);
    }
    __syncthreads();
    if (tid < BN) {
      int b = m0 >> 12;
      atomicAdd(out + b*(H_+K_) + n0 + tid, colsum[tid] * (1.0f/N_));
    }
  }
}

// ---------------- K3: radius graph + mean aggregation, fp8 gather ----------------
__device__ __forceinline__ void accf8(uint2 v, float* a) {
  f32x2 p;
  p = __builtin_amdgcn_cvt_pk_f32_fp8(v.x, false); a[0] += p[0]; a[1] += p[1];
  p = __builtin_amdgcn_cvt_pk_f32_fp8(v.x, true);  a[2] += p[0]; a[3] += p[1];
  p = __builtin_amdgcn_cvt_pk_f32_fp8(v.y, false); a[4] += p[0]; a[5] += p[1];
  p = __builtin_amdgcn_cvt_pk_f32_fp8(v.y, true);  a[6] += p[0]; a[7] += p[1];
}

__global__ __launch_bounds__(256) void k_aggregate(const float* __restrict__ positions,
                                                   const unsigned char* __restrict__ P,
                                                   unsigned short* __restrict__ AB) {
  __shared__ unsigned short nl[8*CAP];   // 3 KB
  __shared__ int cnt[8];
  __shared__ float sdx[8], sdy[8];
  int blk = blockIdx.x;                  // 0..2047
  int xcd = blk & 7;
  int b = xcd >> 1;                      // graph b pinned to XCDs {2b, 2b+1}
  int sub = ((blk >> 3) << 1) | (xcd & 1);   // 0..511
  int dest0 = sub * 8;
  int tid = threadIdx.x, lane = tid & 63, w = tid >> 6;
  const float2* p2 = (const float2*)(positions + (size_t)b*N_*2);
  if (tid < 8) {
    cnt[tid] = 0;
    float2 pd = p2[dest0 + tid];
    sdx[tid] = pd.x; sdy[tid] = pd.y;
  }
  __syncthreads();
  // phase 1: scan all positions, test 8 dests per src point
  for (int it = 0; it < 16; it++) {
    int j = tid + 256*it;
    float2 pj = p2[j];
    #pragma unroll
    for (int d = 0; d < 8; d++) {
      float dx = pj.x - sdx[d], dy = pj.y - sdy[d];
      if (dx*dx + dy*dy < R2_ && j != dest0 + d) {
        int p = atomicAdd(&cnt[d], 1);
        if (p < CAP) nl[d*CAP + p] = (unsigned short)j;
      }
    }
  }
  __syncthreads();
  // phase 2: wave w -> dests w*2, w*2+1; lane covers 8 of 512 cols; fp8 ILP-4 gather
  const unsigned char* featb = P + ((size_t)(b << 12))*512 + lane*8;
  #pragma unroll
  for (int dd = 0; dd < 2; dd++) {
    int d = w*2 + dd;
    int deg = cnt[d]; if (deg > CAP) deg = CAP;
    float inv = 64.0f / (float)(deg > 1 ? deg : 1);   // undo 1/64 quant scale
    const unsigned short* nlp = &nl[d*CAP];
    float a[8] = {};
    int n = 0;
    for (; n + 4 <= deg; n += 4) {
      ushort4 idx = *(const ushort4*)&nlp[n];  // one ds_read_b64
      uint2 v0 = *(const uint2*)(featb + (size_t)idx.x*512);
      uint2 v1 = *(const uint2*)(featb + (size_t)idx.y*512);
      uint2 v2 = *(const uint2*)(featb + (size_t)idx.z*512);
      uint2 v3 = *(const uint2*)(featb + (size_t)idx.w*512);
      accf8(v0, a); accf8(v1, a); accf8(v2, a); accf8(v3, a);
    }
    for (; n < deg; n++) {
      int j = nlp[n];
      uint2 v = *(const uint2*)(featb + (size_t)j*512);
      accf8(v, a);
    }
    uint4 o;
    o.x = ((unsigned)f2bf(a[1]*inv) << 16) | f2bf(a[0]*inv);
    o.y = ((unsigned)f2bf(a[3]*inv) << 16) | f2bf(a[2]*inv);
    o.z = ((unsigned)f2bf(a[5]*inv) << 16) | f2bf(a[4]*inv);
    o.w = ((unsigned)f2bf(a[7]*inv) << 16) | f2bf(a[6]*inv);
    *(uint4*)(AB + (size_t)((b << 12) + dest0 + d)*1024 + lane*8) = o;
  }
}

extern "C" void kernel_launch(void* const* d_in, const int* in_sizes, int n_in,
                              void* d_out, int out_size, void* d_ws, size_t ws_size,
                              hipStream_t stream) {
  const float* images    = (const float*)d_in[0];
  const float* positions = (const float*)d_in[1];
  const float* W_feat    = (const float*)d_in[2];
  const float* b_feat    = (const float*)d_in[3];
  const float* W_pos     = (const float*)d_in[4];
  const float* W_gnn     = (const float*)d_in[5];
  const float* W_self    = (const float*)d_in[6];
  const float* anchors   = (const float*)d_in[7];
  float* out = (float*)d_out;

  char* ws = (char*)d_ws;
  unsigned short* imgs_bf = (unsigned short*)ws;                     // 16384*1536*2 = 50331648
  unsigned short* AB      = (unsigned short*)(ws + 50331648);        // 16384*1024*2 = 33554432
  unsigned short* WfT     = (unsigned short*)(ws + 83886080);        // 512*1536*2  = 1572864
  unsigned short* WgsT    = (unsigned short*)(ws + 85458944);        // 512*1024*2  = 1048576
  unsigned char*  P       = (unsigned char*)(ws + 86507520);         // 16384*512 fp8 = 8388608
  float*          invanorm= (float*)(ws + 94896128);                 // 32 B
  unsigned short* ancT    = (unsigned short*)(ws + 94896160);        // 16*1536*2 = 49152
  float*          inv_norm= (float*)(ws + 94945312);                 // 16384*4 = 65536
  // Total ws use = 95,010,848 B; harness workspace (~400 MB per poison fills) covers it.

  hipMemsetAsync(d_out, 0, sizeof(float)*B_*(H_+K_), stream);
  k_prepcast<<<CAST_BLKS + 320 + 8, 256, 0, stream>>>(images, anchors, W_feat, W_gnn, W_self,
                                                      imgs_bf, inv_norm, WfT, WgsT, ancT, invanorm);
  k_gemm<<<512, 256, 0, stream>>>(imgs_bf, WfT, D_, 0, b_feat, W_pos, positions, AB, P,
                                  ancT, inv_norm, invanorm, out);
  k_aggregate<<<2048, 256, 0, stream>>>(positions, P, AB);
  k_gemm<<<512, 256, 0, stream>>>(AB, WgsT, 1024, 1, nullptr, nullptr, nullptr, AB, nullptr,
                                  ancT, inv_norm, invanorm, out);
}

// Round 12
// 271.288 us; speedup vs baseline: 1.1003x; 1.1003x over previous
//
#include <hip/hip_runtime.h>

#define B_ 4
#define N_ 4096
#define D_ 1536
#define H_ 512
#define K_ 8
#define M_ (B_*N_)          // 16384
#define R2_ 160000.0f       // 400^2
#define CAP 192             // max neighbors tracked per node (mean deg ~32, P(>192)~0)

typedef __attribute__((ext_vector_type(8))) short bf16x8;
typedef __attribute__((ext_vector_type(4))) float f32x4;
typedef __attribute__((ext_vector_type(2))) float f32x2;

__device__ __forceinline__ unsigned short f2bf(float f) {
  union { float f; unsigned u; } v; v.f = f;
  unsigned r = (v.u + 0x7FFFu + ((v.u >> 16) & 1u)) >> 16;
  return (unsigned short)r;
}

typedef const __attribute__((address_space(1))) unsigned int gas_u32;
typedef __attribute__((address_space(3))) unsigned int las_u32;
__device__ __forceinline__ void gl_lds16(const unsigned short* g, unsigned short* l) {
  __builtin_amdgcn_global_load_lds((gas_u32*)g, (las_u32*)l, 16, 0, 0);
}

// ---------------- K0: prepcast — cast+rownorm stream, weight transposes, anchor prep ------
#define CAST_BLKS 4096

__global__ __launch_bounds__(256) void k_prepcast(
    const float* __restrict__ images, const float* __restrict__ anchors,
    const float* __restrict__ Wf, const float* __restrict__ Wg, const float* __restrict__ Ws,
    unsigned short* __restrict__ imgs_bf, float* __restrict__ inv_norm,
    unsigned short* __restrict__ WfT, unsigned short* __restrict__ WgsT,
    unsigned short* __restrict__ ancT, float* __restrict__ invanorm) {
  int tid = threadIdx.x;
  if (blockIdx.x >= CAST_BLKS) {
    int bi = blockIdx.x - CAST_BLKS;
    if (bi < 320) {
      // ---- weight transpose ----
      __shared__ float t[64][65];
      int bx = bi & 7, by = bi >> 3;
      const float* W; unsigned short* WT; int kt, outStride, outOff;
      if (by < 24)      { W = Wf; WT = WfT;  kt = by;      outStride = D_;   outOff = 0; }
      else if (by < 32) { W = Wg; WT = WgsT; kt = by - 24; outStride = 1024; outOff = 0; }
      else              { W = Ws; WT = WgsT; kt = by - 32; outStride = 1024; outOff = 512; }
      int tx = tid & 63, ty = tid >> 6;
      #pragma unroll
      for (int r = 0; r < 64; r += 4)
        t[ty + r][tx] = W[(size_t)(kt*64 + ty + r)*H_ + bx*64 + tx];
      __syncthreads();
      #pragma unroll
      for (int r = 0; r < 64; r += 4) {
        int n = bx*64 + ty + r;
        WT[(size_t)n*outStride + outOff + kt*64 + tx] = f2bf(t[tx][ty + r]);
      }
      return;
    }
    // ---- anchor prep: bf16 row k of ancT (+ zero row k+8), 1/norm ----
    __shared__ float red[4];
    int k = bi - 320;
    float s = 0.f;
    for (int i = tid; i < D_; i += 256) {
      float v = anchors[k*D_ + i];
      s += v*v;
      ancT[(size_t)k*D_ + i] = f2bf(v);
      ancT[(size_t)(k+8)*D_ + i] = 0;     // zero anchors for MFMA cols 8..15
    }
    #pragma unroll
    for (int off = 32; off; off >>= 1) s += __shfl_down(s, off);
    if ((tid & 63) == 0) red[tid >> 6] = s;
    __syncthreads();
    if (tid == 0) invanorm[k] = 1.0f / fmaxf(sqrtf(red[0]+red[1]+red[2]+red[3]), 1e-12f);
    return;
  }
  // ---- cast + row norm: one row per wave (16384 waves -> full TLP, ~BW-bound) ----
  int lane = tid & 63, w = tid >> 6;
  int row = blockIdx.x*4 + w;
  const float4* xr = (const float4*)(images + (size_t)row*D_);
  ushort4* ob = (ushort4*)(imgs_bf + (size_t)row*D_);
  float nrm = 0.f;
  #pragma unroll
  for (int it = 0; it < 6; it++) {
    float4 x = xr[lane + 64*it];
    nrm += x.x*x.x + x.y*x.y + x.z*x.z + x.w*x.w;
    ushort4 s;
    s.x = f2bf(x.x); s.y = f2bf(x.y); s.z = f2bf(x.z); s.w = f2bf(x.w);
    ob[lane + 64*it] = s;
  }
  #pragma unroll
  for (int off = 32; off; off >>= 1) nrm += __shfl_down(nrm, off);
  if (lane == 0) inv_norm[row] = 1.0f / fmaxf(sqrtf(nrm), 1e-12f);
}

// ---------------- GEMM: C(16384 x 512) = A(16384 x Kdim) @ BT^T ----------------
// XCD-pinned remap (R8) + 3-buffer counted-vmcnt pipeline (R9/R10) + NEW: rule-#21
// both-sides XOR swizzle. R11 lesson: fragment-major staging killed conflicts (3.4M->262K)
// but scattered the GLOBAL pattern (16 rows/quarter-wave -> 4x transactions, +12us/gemm).
// Correct form: keep R10's coalesced staging runs (4 lanes = one row's 64B) but XOR the
// k-segment each lane fetches: seg = (lane&3) ^ ((lane>>3)&3). LDS pos p then holds
// (row p>>2, seg (p&3)^((p>>3)&3)); read addr = row*64B + (quad ^ ((l15>>1)&3))*16B.
// Per quarter-wave the 8 16B-slots/128B are each hit exactly 2x -> 2-way = free (m136).
// Fragment contents per lane bit-identical to R10.
#define BM 128
#define BN 128
#define BK 32

__global__ __launch_bounds__(256) void k_gemm(
    const unsigned short* __restrict__ A, const unsigned short* __restrict__ BT,
    int Kdim, int mode, const float* __restrict__ bias, const float* __restrict__ Wpos,
    const float* __restrict__ positions, unsigned short* __restrict__ AB,
    unsigned char* __restrict__ P, const unsigned short* __restrict__ ancT,
    const float* __restrict__ invnorm, const float* __restrict__ invanorm,
    float* __restrict__ out) {
  __shared__ __align__(16) unsigned short As[3][BM*BK];   // 3 x 8 KB
  __shared__ __align__(16) unsigned short Bs[3][BN*BK];
  __shared__ float colsum[BN];
  int tid = threadIdx.x;
  int lane = tid & 63, wv = tid >> 6;
  int l15 = lane & 15, quad = lane >> 4;
  int bx = blockIdx.x;

  int wm = wv >> 1, wn = wv & 1;
  // XCD-pinned: xcd = bx&7; j = bx>>3 walks 64 blocks on this XCD as 16 A-tiles x 4 bn.
  int j = bx >> 3;
  int bm = (bx & 7) + 8*(j >> 2), bn = j & 3;
  int m0 = bm*BM, n0 = bn*BN;

  const bool doC = (mode == 0) && (bn == 0);   // block-uniform

  f32x4 acc[4][4] = {};
  f32x4 cacc[2] = {};                          // concept accumulators (bn==0 blocks)
  const unsigned short* anc = ancT + l15*D_ + quad*8;  // anchor row l15 (rows 8..15 zero)

  int c = wv*2;
  // coalesced staging runs (4 lanes = one row's 64B) with XOR'd k-segment per lane:
  int rowc = lane >> 2, seg = (lane & 3) ^ ((lane >> 3) & 3);
  const unsigned short* gA0 = A  + (size_t)(m0 + c*16 + rowc)*Kdim + seg*8;
  const unsigned short* gA1 = gA0 + (size_t)16*Kdim;
  const unsigned short* gB0 = BT + (size_t)(n0 + c*16 + rowc)*Kdim + seg*8;
  const unsigned short* gB1 = gB0 + (size_t)16*Kdim;
  int rswz = (quad ^ ((l15 >> 1) & 3)) * 8;    // swizzled k-slot on the read side

#define STAGE(b) do { \
    unsigned short* nA = As[b] + c*512; \
    unsigned short* nB = Bs[b] + c*512; \
    gl_lds16(gA0, nA); gl_lds16(gA1, nA + 512); \
    gl_lds16(gB0, nB); gl_lds16(gB1, nB + 512); \
    gA0 += BK; gA1 += BK; gB0 += BK; gB1 += BK; } while (0)

  int nk = Kdim / BK;
  union { uint4 u; bf16x8 h; } ancCur, ancNext;
  // prologue: anchor frag 0 (asm, issued FIRST so it retires before stage(0)) + tiles 0,1
  if (doC)
    asm volatile("global_load_dwordx4 %0, %1, off" : "=v"(ancNext.u) : "v"(anc) : "memory");
  STAGE(0);
  STAGE(1);
  const unsigned short* ancp = anc + BK;

  int cb = 0, nb = 2;
  for (int kt = 0; kt < nk; kt++) {
    if (kt + 1 < nk) asm volatile("s_waitcnt vmcnt(4)" ::: "memory");
    else             asm volatile("s_waitcnt vmcnt(0)" ::: "memory");
    __builtin_amdgcn_s_barrier();
    asm volatile("" ::: "memory");   // pin following LDS reads below the barrier

    ancCur = ancNext;
    if (doC && kt + 1 < nk) {
      asm volatile("global_load_dwordx4 %0, %1, off" : "=v"(ancNext.u) : "v"(ancp) : "memory");
      ancp += BK;
    }
    if (kt + 2 < nk) { STAGE(nb); nb = (nb + 1 == 3) ? 0 : nb + 1; }

    const unsigned short* Ab = As[cb];
    const unsigned short* Bb = Bs[cb];
    cb = (cb + 1 == 3) ? 0 : cb + 1;

    bf16x8 aF[4], bF[4];
    #pragma unroll
    for (int f = 0; f < 4; f++)
      aF[f] = *(const bf16x8*)&Ab[(wm*64 + f*16 + l15)*BK + rswz];
    #pragma unroll
    for (int f = 0; f < 4; f++)
      bF[f] = *(const bf16x8*)&Bb[(wn*64 + f*16 + l15)*BK + rswz];
    #pragma unroll
    for (int mi = 0; mi < 4; mi++)
      #pragma unroll
      for (int ni = 0; ni < 4; ni++)
        acc[mi][ni] = __builtin_amdgcn_mfma_f32_16x16x32_bf16(aF[mi], bF[ni], acc[mi][ni], 0, 0, 0);

    if (doC) {
      bf16x8 ancF = ancCur.h;
      if (wn == 0) {   // wave-uniform: rows wm*64 + 0..31
        cacc[0] = __builtin_amdgcn_mfma_f32_16x16x32_bf16(aF[0], ancF, cacc[0], 0, 0, 0);
        cacc[1] = __builtin_amdgcn_mfma_f32_16x16x32_bf16(aF[1], ancF, cacc[1], 0, 0, 0);
      } else {         // rows wm*64 + 32..63
        cacc[0] = __builtin_amdgcn_mfma_f32_16x16x32_bf16(aF[2], ancF, cacc[0], 0, 0, 0);
        cacc[1] = __builtin_amdgcn_mfma_f32_16x16x32_bf16(aF[3], ancF, cacc[1], 0, 0, 0);
      }
    }
  }
#undef STAGE

  if (doC) {
    // cacc C layout: col k = l15, row = quad*4 + reg within group f.
    float invA = (l15 < K_) ? invanorm[l15] : 0.f;
    float part = 0.f;
    #pragma unroll
    for (int f = 0; f < 2; f++) {
      const float4 q = *(const float4*)&invnorm[m0 + wm*64 + wn*32 + f*16 + quad*4];
      part += cacc[f][0]*q.x + cacc[f][1]*q.y + cacc[f][2]*q.z + cacc[f][3]*q.w;
    }
    part *= invA;
    part += __shfl_down(part, 32);
    part += __shfl_down(part, 16);
    if (lane < K_) atomicAdd(out + (m0 >> 12)*(H_+K_) + H_ + lane, part * (1.0f/N_));
  }

  if (mode == 0) {
    float bz[4], w0v[4], w1v[4];
    #pragma unroll
    for (int ni = 0; ni < 4; ni++) {
      int gh = n0 + wn*64 + ni*16 + l15;
      bz[ni] = bias[gh]; w0v[ni] = Wpos[gh]; w1v[ni] = Wpos[H_ + gh];
    }
    // As[0] (tile consumed 2+ barriers ago) reused as wave-private bounce scratch
    float* sb = ((float*)As[0]) + wv*256;       // 1 KB wave-private scratch
    int col4 = n0 + wn*64 + l15*4;              // base of this lane's 4 consecutive cols
    #pragma unroll
    for (int mi = 0; mi < 4; mi++) {
      #pragma unroll
      for (int r = 0; r < 4; r++) {
        int gm = m0 + wm*64 + mi*16 + quad*4 + r;
        float2 p = ((const float2*)positions)[gm];
        #pragma unroll
        for (int ni = 0; ni < 4; ni++) {
          float v = acc[mi][ni][r] + bz[ni] + p.x*w0v[ni] + p.y*w1v[ni];
          sb[quad*64 + ni*16 + l15] = v;        // ds_write_b32 x4 (wave-local)
        }
        f32x4 q = *(f32x4*)&sb[quad*64 + l15*4];  // ds_read_b128: 4 consecutive cols
        uint2 o;
        o.x = ((unsigned)f2bf(q[1]) << 16) | f2bf(q[0]);
        o.y = ((unsigned)f2bf(q[3]) << 16) | f2bf(q[2]);
        *(uint2*)&AB[(size_t)gm*1024 + 512 + col4] = o;   // feat bf16 (pre-relu, gemm2 A-half)
        float e0 = fminf(fmaxf(q[0], 0.f)*0.015625f, 448.f);
        float e1 = fminf(fmaxf(q[1], 0.f)*0.015625f, 448.f);
        float e2 = fminf(fmaxf(q[2], 0.f)*0.015625f, 448.f);
        float e3 = fminf(fmaxf(q[3], 0.f)*0.015625f, 448.f);
        int u = __builtin_amdgcn_cvt_pk_fp8_f32(e0, e1, 0, false);
        u     = __builtin_amdgcn_cvt_pk_fp8_f32(e2, e3, u, true);
        *(unsigned*)(P + (size_t)gm*512 + col4) = (unsigned)u;  // relu(feat)/64 fp8
      }
    }
  } else {
    if (tid < BN) colsum[tid] = 0.f;
    __syncthreads();
    #pragma unroll
    for (int ni = 0; ni < 4; ni++) {
      float s = 0.f;
      #pragma unroll
      for (int mi = 0; mi < 4; mi++) {
        #pragma unroll
        for (int r = 0; r < 4; r++) s += fmaxf(acc[mi][ni][r], 0.f);
      }
      s += __shfl_down(s, 32);
      s += __shfl_down(s, 16);
      if (quad == 0) atomicAdd(&colsum[wn*64 + ni*16 + l15], s);
    }
    __syncthreads();
    if (tid < BN) {
      int b = m0 >> 12;
      atomicAdd(out + b*(H_+K_) + n0 + tid, colsum[tid] * (1.0f/N_));
    }
  }
}

// ---------------- K3: radius graph + mean aggregation, fp8 gather ----------------
__device__ __forceinline__ void accf8(uint2 v, float* a) {
  f32x2 p;
  p = __builtin_amdgcn_cvt_pk_f32_fp8(v.x, false); a[0] += p[0]; a[1] += p[1];
  p = __builtin_amdgcn_cvt_pk_f32_fp8(v.x, true);  a[2] += p[0]; a[3] += p[1];
  p = __builtin_amdgcn_cvt_pk_f32_fp8(v.y, false); a[4] += p[0]; a[5] += p[1];
  p = __builtin_amdgcn_cvt_pk_f32_fp8(v.y, true);  a[6] += p[0]; a[7] += p[1];
}

__global__ __launch_bounds__(256) void k_aggregate(const float* __restrict__ positions,
                                                   const unsigned char* __restrict__ P,
                                                   unsigned short* __restrict__ AB) {
  __shared__ unsigned short nl[8*CAP];   // 3 KB
  __shared__ int cnt[8];
  __shared__ float sdx[8], sdy[8];
  int blk = blockIdx.x;                  // 0..2047
  int xcd = blk & 7;
  int b = xcd >> 1;                      // graph b pinned to XCDs {2b, 2b+1}
  int sub = ((blk >> 3) << 1) | (xcd & 1);   // 0..511
  int dest0 = sub * 8;
  int tid = threadIdx.x, lane = tid & 63, w = tid >> 6;
  const float2* p2 = (const float2*)(positions + (size_t)b*N_*2);
  if (tid < 8) {
    cnt[tid] = 0;
    float2 pd = p2[dest0 + tid];
    sdx[tid] = pd.x; sdy[tid] = pd.y;
  }
  __syncthreads();
  // phase 1: scan all positions, test 8 dests per src point
  for (int it = 0; it < 16; it++) {
    int j = tid + 256*it;
    float2 pj = p2[j];
    #pragma unroll
    for (int d = 0; d < 8; d++) {
      float dx = pj.x - sdx[d], dy = pj.y - sdy[d];
      if (dx*dx + dy*dy < R2_ && j != dest0 + d) {
        int p = atomicAdd(&cnt[d], 1);
        if (p < CAP) nl[d*CAP + p] = (unsigned short)j;
      }
    }
  }
  __syncthreads();
  // phase 2: wave w -> dests w*2, w*2+1; lane covers 8 of 512 cols; fp8 ILP-4 gather
  const unsigned char* featb = P + ((size_t)(b << 12))*512 + lane*8;
  #pragma unroll
  for (int dd = 0; dd < 2; dd++) {
    int d = w*2 + dd;
    int deg = cnt[d]; if (deg > CAP) deg = CAP;
    float inv = 64.0f / (float)(deg > 1 ? deg : 1);   // undo 1/64 quant scale
    const unsigned short* nlp = &nl[d*CAP];
    float a[8] = {};
    int n = 0;
    for (; n + 4 <= deg; n += 4) {
      ushort4 idx = *(const ushort4*)&nlp[n];  // one ds_read_b64
      uint2 v0 = *(const uint2*)(featb + (size_t)idx.x*512);
      uint2 v1 = *(const uint2*)(featb + (size_t)idx.y*512);
      uint2 v2 = *(const uint2*)(featb + (size_t)idx.z*512);
      uint2 v3 = *(const uint2*)(featb + (size_t)idx.w*512);
      accf8(v0, a); accf8(v1, a); accf8(v2, a); accf8(v3, a);
    }
    for (; n < deg; n++) {
      int j = nlp[n];
      uint2 v = *(const uint2*)(featb + (size_t)j*512);
      accf8(v, a);
    }
    uint4 o;
    o.x = ((unsigned)f2bf(a[1]*inv) << 16) | f2bf(a[0]*inv);
    o.y = ((unsigned)f2bf(a[3]*inv) << 16) | f2bf(a[2]*inv);
    o.z = ((unsigned)f2bf(a[5]*inv) << 16) | f2bf(a[4]*inv);
    o.w = ((unsigned)f2bf(a[7]*inv) << 16) | f2bf(a[6]*inv);
    *(uint4*)(AB + (size_t)((b << 12) + dest0 + d)*1024 + lane*8) = o;
  }
}

extern "C" void kernel_launch(void* const* d_in, const int* in_sizes, int n_in,
                              void* d_out, int out_size, void* d_ws, size_t ws_size,
                              hipStream_t stream) {
  const float* images    = (const float*)d_in[0];
  const float* positions = (const float*)d_in[1];
  const float* W_feat    = (const float*)d_in[2];
  const float* b_feat    = (const float*)d_in[3];
  const float* W_pos     = (const float*)d_in[4];
  const float* W_gnn     = (const float*)d_in[5];
  const float* W_self    = (const float*)d_in[6];
  const float* anchors   = (const float*)d_in[7];
  float* out = (float*)d_out;

  char* ws = (char*)d_ws;
  unsigned short* imgs_bf = (unsigned short*)ws;                     // 16384*1536*2 = 50331648
  unsigned short* AB      = (unsigned short*)(ws + 50331648);        // 16384*1024*2 = 33554432
  unsigned short* WfT     = (unsigned short*)(ws + 83886080);        // 512*1536*2  = 1572864
  unsigned short* WgsT    = (unsigned short*)(ws + 85458944);        // 512*1024*2  = 1048576
  unsigned char*  P       = (unsigned char*)(ws + 86507520);         // 16384*512 fp8 = 8388608
  float*          invanorm= (float*)(ws + 94896128);                 // 32 B
  unsigned short* ancT    = (unsigned short*)(ws + 94896160);        // 16*1536*2 = 49152
  float*          inv_norm= (float*)(ws + 94945312);                 // 16384*4 = 65536
  // Total ws use = 95,010,848 B; harness workspace (~400 MB per poison fills) covers it.

  hipMemsetAsync(d_out, 0, sizeof(float)*B_*(H_+K_), stream);
  k_prepcast<<<CAST_BLKS + 320 + 8, 256, 0, stream>>>(images, anchors, W_feat, W_gnn, W_self,
                                                      imgs_bf, inv_norm, WfT, WgsT, ancT, invanorm);
  k_gemm<<<512, 256, 0, stream>>>(imgs_bf, WfT, D_, 0, b_feat, W_pos, positions, AB, P,
                                  ancT, inv_norm, invanorm, out);
  k_aggregate<<<2048, 256, 0, stream>>>(positions, P, AB);
  k_gemm<<<512, 256, 0, stream>>>(AB, WgsT, 1024, 1, nullptr, nullptr, nullptr, AB, nullptr,
                                  ancT, inv_norm, invanorm, out);
}